// Round 11
// baseline (1012.596 us; speedup 1.0000x reference)
//
#include <hip/hip_runtime.h>
#include <hip/hip_bf16.h>

#define NN 100000
#define EE 1600000
#define BB 256
#define F_NODE 35
#define F_EDGE 10
#define HH 64
#define IN_DIM 138
#define N_CONV 3
#define EPSBN 1e-5f
#define NB1 ((NN + 255) / 256)  // 391 scan blocks

// conv tiling: 3072 blocks x 2 waves = exactly 12 blocks/CU (one round at VGPR 80)
#define NBLK 3072
#define NGROUPS 34
#define SUBLEN 136          // 4*NGROUPS
#define EPB 544             // 16*NGROUPS edges per block
#define EPADTOT (NBLK * EPB)        // 1,671,168
#define NPAD (EPADTOT - EE)         // 71,168 = 278*256
#define EFSTR 12            // padded ef row in halves (24 B)

// fat prep kernel block ranges
#define PREP_EMBED_BLKS 25000                      // NH/256
#define PREP_HIST_BLKS  6250                       // EE/256
#define PREP_W_BLKS     240                        // 3*128*160/256
#define PREP_PAD_BLKS   278                        // NPAD/256
#define PREP_TOT (PREP_EMBED_BLKS + PREP_HIST_BLKS + PREP_W_BLKS + PREP_PAD_BLKS)

#define SYNC_GRID 512       // resident-grid size for spin-barrier kernels

#define LOG2E 1.442695041f
#define LN2   0.6931471806f

typedef _Float16 half8 __attribute__((ext_vector_type(8)));
typedef float floatx4 __attribute__((ext_vector_type(4)));

__device__ __forceinline__ float softplus_fast(float x) {
    float t = __builtin_amdgcn_exp2f(fminf(LOG2E * x, 126.0f));
    return LN2 * __builtin_amdgcn_logf(1.0f + t);
}
// inputs pre-scaled: g2 = -log2e*g, c2 = log2e*c  ->  sigmoid(g)*log2(1+2^c2)
__device__ __forceinline__ float mpair_pre(float g2, float c2) {
    float tg = __builtin_amdgcn_exp2f(g2);
    float sig = __builtin_amdgcn_rcpf(1.0f + tg);
    float tc = __builtin_amdgcn_exp2f(fminf(c2, 126.0f));
    float l = __builtin_amdgcn_logf(1.0f + tc);
    return sig * l;
}

// all-blocks-resident grid barrier (grid must be <= co-resident capacity!)
__device__ __forceinline__ void grid_barrier(int* counter, int nblocks) {
    __syncthreads();   // drains this block's outstanding mem ops (vmcnt(0) before s_barrier)
    if (threadIdx.x == 0) {
        __hip_atomic_fetch_add(counter, 1, __ATOMIC_ACQ_REL, __HIP_MEMORY_SCOPE_AGENT);
        while (__hip_atomic_load(counter, __ATOMIC_ACQUIRE, __HIP_MEMORY_SCOPE_AGENT) < nblocks)
            __builtin_amdgcn_s_sleep(8);
    }
    __syncthreads();
}

// ---------------- fat prep: embed | hist+rank | weight-prep | pad-fill ----------------
__global__ __launch_bounds__(256)
void prep_kernel(const float* __restrict__ nf, const float* __restrict__ ew,
                 const float* __restrict__ eb, _Float16* __restrict__ h16,
                 const int* __restrict__ src, int* __restrict__ cnt, int* __restrict__ rank,
                 const float* __restrict__ gw, const float* __restrict__ cw,
                 _Float16* __restrict__ wT,
                 int* __restrict__ ssorted, int2* __restrict__ sdsorted,
                 _Float16* __restrict__ ef16) {
    int bid = blockIdx.x;
    int tid = threadIdx.x;
    if (bid < PREP_EMBED_BLKS) {
        // ---- embed: h16 = nf @ W + b ----
        __shared__ float wl[F_NODE * HH];
        for (int i = tid; i < F_NODE * HH; i += 256) wl[i] = ew[i];
        __syncthreads();
        int idx = bid * 256 + tid;
        int node = idx >> 6, j = idx & 63;
        if (node >= NN) return;
        float acc = eb[j];
        const float* row = nf + node * F_NODE;
#pragma unroll
        for (int k = 0; k < F_NODE; k++) acc += row[k] * wl[k * HH + j];
        h16[idx] = (_Float16)acc;
    } else if (bid < PREP_EMBED_BLKS + PREP_HIST_BLKS) {
        // ---- hist + rank ----
        int e = (bid - PREP_EMBED_BLKS) * 256 + tid;
        rank[e] = atomicAdd(&cnt[src[e]], 1);
    } else if (bid < PREP_EMBED_BLKS + PREP_HIST_BLKS + PREP_W_BLKS) {
        // ---- weights -> f16 transposed, pre-scaled by -/+log2e ----
        int idx = (bid - PREP_EMBED_BLKS - PREP_HIST_BLKS) * 256 + tid;
        int k = idx % 160;
        int n = (idx / 160) & 127;
        int layer = idx / (160 * 128);
        float v = 0.f;
        if (k < IN_DIM)
            v = (n < 64) ? (-LOG2E) * gw[layer * IN_DIM * HH + k * HH + n]
                         : ( LOG2E) * cw[layer * IN_DIM * HH + k * HH + (n - 64)];
        wT[idx] = (_Float16)v;
    } else {
        // ---- pad edges [EE, EPADTOT) -> dummy node NN; zero h16 row NN ----
        int t = (bid - PREP_EMBED_BLKS - PREP_HIST_BLKS - PREP_W_BLKS) * 256 + tid;
        int pos = EE + t;
        ssorted[pos] = NN;
        int2 sd; sd.x = NN; sd.y = NN;
        sdsorted[pos] = sd;
        uint2 z2; z2.x = 0u; z2.y = 0u;
        uint2* op = (uint2*)(ef16 + (size_t)pos * EFSTR);
        op[0] = z2; op[1] = z2; op[2] = z2;
        if (t < 32) ((uint2*)(h16 + (size_t)NN * HH))[t] = z2;
    }
}

// ---------------- fused scan: per-block scan + last-arriving block scans bsum ----------------
__global__ __launch_bounds__(256)
void scan_kernel(int* __restrict__ cnt, int* __restrict__ bsum, int* __restrict__ done) {
    __shared__ int ls[256];
    __shared__ int lastflag;
    int t = threadIdx.x;
    int i = blockIdx.x * 256 + t;
    int v = (i < NN) ? cnt[i] : 0;
    ls[t] = v;
    __syncthreads();
#pragma unroll
    for (int off = 1; off < 256; off <<= 1) {
        int add = (t >= off) ? ls[t - off] : 0;
        __syncthreads();
        ls[t] += add;
        __syncthreads();
    }
    if (i < NN) cnt[i] = ls[t] - v;   // exclusive within block
    if (t == 255)
        __hip_atomic_store(&bsum[blockIdx.x], ls[255], __ATOMIC_RELEASE, __HIP_MEMORY_SCOPE_AGENT);
    __syncthreads();
    if (t == 0) {
        int old = __hip_atomic_fetch_add(done, 1, __ATOMIC_ACQ_REL, __HIP_MEMORY_SCOPE_AGENT);
        lastflag = (old == NB1 - 1);
    }
    __syncthreads();
    if (!lastflag) return;
    // last block: exclusive-scan the 391 block sums (512-slot Hillis-Steele, 2 slots/thread)
    __shared__ int bs[512];
    int v0 = (t < NB1) ? __hip_atomic_load(&bsum[t], __ATOMIC_ACQUIRE, __HIP_MEMORY_SCOPE_AGENT) : 0;
    int v1 = (256 + t < NB1) ? __hip_atomic_load(&bsum[256 + t], __ATOMIC_ACQUIRE, __HIP_MEMORY_SCOPE_AGENT) : 0;
    bs[t] = v0; bs[256 + t] = v1;
    __syncthreads();
#pragma unroll
    for (int off = 1; off < 512; off <<= 1) {
        int a0 = bs[t];       int add0 = (t >= off) ? bs[t - off] : 0;
        int a1 = bs[256 + t]; int add1 = (256 + t >= off) ? bs[256 + t - off] : 0;
        __syncthreads();
        bs[t] = a0 + add0; bs[256 + t] = a1 + add1;
        __syncthreads();
    }
    if (t < NB1) bsum[t] = (t == 0) ? 0 : bs[t - 1];
    if (256 + t < NB1) bsum[256 + t] = bs[256 + t - 1];
}

__global__ __launch_bounds__(256)
void perm_kernel(const int* __restrict__ src, const int* __restrict__ rank,
                 const int* __restrict__ offs, const int* __restrict__ bsum,
                 int* __restrict__ perm) {
    int e = blockIdx.x * 256 + threadIdx.x;
    int s = src[e];
    perm[offs[s] + bsum[s >> 8] + rank[e]] = e;
}

__global__ __launch_bounds__(256)
void gather_kernel(const int* __restrict__ perm,
                   const int* __restrict__ src, const int* __restrict__ dst,
                   const float* __restrict__ ef,
                   int* __restrict__ ssorted, int2* __restrict__ sdsorted,
                   _Float16* __restrict__ ef16) {
    int pos = blockIdx.x * 256 + threadIdx.x;
    int e = perm[pos];
    int s = src[e], d = dst[e];
    ssorted[pos] = s;
    int2 sd; sd.x = s; sd.y = d;
    sdsorted[pos] = sd;
    const float2* efe = (const float2*)(ef + (size_t)e * F_EDGE);
    uint* op = (uint*)(ef16 + (size_t)pos * EFSTR);
#pragma unroll
    for (int i = 0; i < 5; i++) {
        float2 v = efe[i];
        _Float16 h0 = (_Float16)v.x;
        _Float16 h1 = (_Float16)v.y;
        op[i] = (uint)*(unsigned short*)&h0 | ((uint)*(unsigned short*)&h1 << 16);
    }
    op[5] = 0u;
}

// ---------------- conv: R8 body (1-deep prefetch) + pad guard ----------------
__device__ __forceinline__ void loadA(uint4* A,
                                      const _Float16* __restrict__ h16,
                                      const _Float16* __restrict__ ef16,
                                      int s, int d, int eg, int quad) {
    const uint4* hs = (const uint4*)(h16 + (size_t)s * HH);
    const uint4* hd = (const uint4*)(h16 + (size_t)d * HH);
    A[0] = hs[quad];
    A[1] = hs[quad + 4];
    A[2] = hd[quad];
    A[3] = hd[quad + 4];
    uint4 z; z.x = z.y = z.z = z.w = 0u;
    A[4] = z;
    const _Float16* p = ef16 + (size_t)eg * EFSTR;
    if (quad == 0) {
        uint2 a = *(const uint2*)p;
        uint2 b = *(const uint2*)(p + 4);
        A[4].x = a.x; A[4].y = a.y; A[4].z = b.x; A[4].w = b.y;
    } else if (quad == 1) {
        uint2 a = *(const uint2*)(p + 8);
        A[4].x = a.x; A[4].y = a.y;
    }
}

__global__ __launch_bounds__(128, 3)
void edge_conv_mfma(const _Float16* __restrict__ h16,
                    const int* __restrict__ ssorted,
                    const int2* __restrict__ sdsorted,
                    const _Float16* __restrict__ ef16,
                    const _Float16* __restrict__ wT,
                    const float* __restrict__ gb, const float* __restrict__ cb,
                    float* __restrict__ agg) {
    int lane = threadIdx.x & 63;
    int w = threadIdx.x >> 6;          // wave 0/1: col-split
    int quad = lane >> 4, n15 = lane & 15;
    int blockE = blockIdx.x * EPB;
    int base = blockE + ((n15 >> 2) * SUBLEN) + (n15 & 3);
    int ebase_epi = blockE + quad * SUBLEN;   // + g*4 + r : this lane's C rows

    int tg = 2 * w;
    half8 B[4][5];
#pragma unroll
    for (int j = 0; j < 2; j++) {
        const _Float16* wrg = wT + ((tg + j) * 16 + n15) * 160 + quad * 8;
        const _Float16* wrc = wT + ((4 + tg + j) * 16 + n15) * 160 + quad * 8;
#pragma unroll
        for (int ks = 0; ks < 5; ks++) {
            B[j][ks]     = *(const half8*)(wrg + ks * 32);
            B[2 + j][ks] = *(const half8*)(wrc + ks * 32);
        }
    }
    float gb0 = -LOG2E * gb[tg * 16 + n15], gb1 = -LOG2E * gb[(tg + 1) * 16 + n15];
    float cb0 =  LOG2E * cb[tg * 16 + n15], cb1 =  LOG2E * cb[(tg + 1) * 16 + n15];
    int colbase = tg * 16 + n15;

    int sprev = -1;
    float am0 = 0.f, am1 = 0.f;

    uint4 A[5];
    {
        int2 sd0 = sdsorted[base];
        loadA(A, h16, ef16, sd0.x, sd0.y, base, quad);
    }
    int2 sdn = sdsorted[base + 4];

    for (int g = 0; g < NGROUPS; g++) {
        int4 ss = *(const int4*)&ssorted[ebase_epi + g * 4];

        floatx4 acc[4];
        acc[0] = (floatx4){gb0, gb0, gb0, gb0};
        acc[1] = (floatx4){gb1, gb1, gb1, gb1};
        acc[2] = (floatx4){cb0, cb0, cb0, cb0};
        acc[3] = (floatx4){cb1, cb1, cb1, cb1};

#pragma unroll
        for (int ks = 0; ks < 5; ks++) {
            half8 a = __builtin_bit_cast(half8, A[ks]);
#pragma unroll
            for (int t = 0; t < 4; t++)
                acc[t] = __builtin_amdgcn_mfma_f32_16x16x32_f16(a, B[t][ks], acc[t], 0, 0, 0);
        }

        int gl = (g + 1 < NGROUPS) ? g + 1 : NGROUPS - 1;
        loadA(A, h16, ef16, sdn.x, sdn.y, base + gl * 4, quad);
        int gp = (g + 2 < NGROUPS) ? g + 2 : NGROUPS - 1;
        sdn = sdsorted[base + gp * 4];

        float mm0[4], mm1[4];
#pragma unroll
        for (int r = 0; r < 4; r++) {
            mm0[r] = mpair_pre(acc[0][r], acc[2][r]);
            mm1[r] = mpair_pre(acc[1][r], acc[3][r]);
        }
        int srr[4] = {ss.x, ss.y, ss.z, ss.w};
#pragma unroll
        for (int r = 0; r < 4; r++) {
            int sr = srr[r];
            if (sr != sprev) {
                if ((unsigned)sprev < (unsigned)NN) {   // skip init(-1) and pad(NN)
                    float* p = agg + (size_t)sprev * HH + colbase;
                    atomicAdd(p, am0);
                    atomicAdd(p + 16, am1);
                }
                sprev = sr;
                am0 = am1 = 0.f;
            }
            am0 = fmaf(mm0[r], LN2, am0);
            am1 = fmaf(mm1[r], LN2, am1);
        }
    }
    if ((unsigned)sprev < (unsigned)NN) {
        float* p = agg + (size_t)sprev * HH + colbase;
        atomicAdd(p, am0);
        atomicAdd(p + 16, am1);
    }
}

// ---------------- fused BN: stats + grid barrier + update (512 resident blocks) ----------------
__global__ __launch_bounds__(256)
void bn_fused_kernel(_Float16* __restrict__ h16, float* __restrict__ agg,
                     float* __restrict__ stats,
                     const float* __restrict__ g, const float* __restrict__ b,
                     int* __restrict__ counter, float invN) {
    __shared__ float ls[256], lss[256];
    int tid = threadIdx.x;
    float s = 0.f, ss = 0.f;
    // stride 512*256 is a multiple of 64 -> thread keeps one feature (tid&63)
    for (int idx = blockIdx.x * 256 + tid; idx < NN * HH; idx += SYNC_GRID * 256) {
        float v = agg[idx];
        s += v;
        ss += v * v;
    }
    ls[tid] = s;
    lss[tid] = ss;
    __syncthreads();
    if (tid < 64) {
        s = ls[tid] + ls[tid + 64] + ls[tid + 128] + ls[tid + 192];
        ss = lss[tid] + lss[tid + 64] + lss[tid + 128] + lss[tid + 192];
        atomicAdd(&stats[tid], s);
        atomicAdd(&stats[64 + tid], ss);
    }
    grid_barrier(counter, SYNC_GRID);
    // phase2: BN + softplus + agg re-zero
    int j = tid & 63;
    float sj  = __hip_atomic_load(&stats[j], __ATOMIC_RELAXED, __HIP_MEMORY_SCOPE_AGENT);
    float ssj = __hip_atomic_load(&stats[64 + j], __ATOMIC_RELAXED, __HIP_MEMORY_SCOPE_AGENT);
    float mu = sj * invN;
    float var = fmaxf(ssj * invN - mu * mu, 0.0f);
    float scale = g[j] * rsqrtf(var + EPSBN);
    float bj = b[j];
    for (int idx = blockIdx.x * 256 + tid; idx < NN * HH; idx += SYNC_GRID * 256) {
        float a = agg[idx];
        agg[idx] = 0.f;
        float v = (float)h16[idx] + (a - mu) * scale + bj;
        h16[idx] = (_Float16)softplus_fast(v);
    }
}

// ---------------- fused pool + MLP (512 resident blocks) ----------------
__global__ __launch_bounds__(256)
void poolmlp_kernel(const _Float16* __restrict__ h16, const int* __restrict__ gi,
                    float* __restrict__ pool, float* __restrict__ counts,
                    int* __restrict__ counter,
                    const float* __restrict__ w1, const float* __restrict__ b1,
                    const float* __restrict__ w2, const float* __restrict__ b2,
                    const float* __restrict__ w3, const float* __restrict__ b3,
                    float* __restrict__ out) {
    int tid = threadIdx.x;
    int grp = tid >> 6;
    int j = tid & 63;
    // phase1: pooled scatter with run merge over 16-node strips
    for (int sb = blockIdx.x; sb < (NN + 63) / 64; sb += SYNC_GRID) {
        int n0 = sb * 64 + grp * 16;
        if (n0 >= NN) continue;
        int nend = n0 + 16; if (nend > NN) nend = NN;
        int gprev = gi[n0];
        float a = 0.f;
        int cnt = 0;
        for (int nn = n0; nn < nend; nn++) {
            int gg = gi[nn];
            if (gg != gprev) {
                atomicAdd(&pool[gprev * 64 + j], a);
                if (j == 0) atomicAdd(&counts[gprev], (float)cnt);
                a = 0.f; cnt = 0; gprev = gg;
            }
            a += (float)h16[(size_t)nn * 64 + j];
            cnt++;
        }
        atomicAdd(&pool[gprev * 64 + j], a);
        if (j == 0) atomicAdd(&counts[gprev], (float)cnt);
    }
    grid_barrier(counter, SYNC_GRID);
    // phase2: blocks 0..255 run the 3-layer MLP for graph b
    if (blockIdx.x >= BB) return;
    int b = blockIdx.x;
    __shared__ float x0[64], x1[128], x2[64];
    if (tid < 64) {
        float c = __hip_atomic_load(&counts[b], __ATOMIC_RELAXED, __HIP_MEMORY_SCOPE_AGENT);
        c = c < 1.f ? 1.f : c;
        float pv = __hip_atomic_load(&pool[b * 64 + tid], __ATOMIC_RELAXED, __HIP_MEMORY_SCOPE_AGENT);
        x0[tid] = pv / c;
    }
    __syncthreads();
    if (tid < 128) {
        float acc = 0.f;
#pragma unroll
        for (int k = 0; k < 64; k++) acc += x0[k] * w1[k * 128 + tid];
        x1[tid] = softplus_fast(acc + b1[tid]);
    }
    __syncthreads();
    if (tid < 64) {
        float acc = 0.f;
#pragma unroll
        for (int k = 0; k < 128; k++) acc += x1[k] * w2[k * 64 + tid];
        x2[tid] = softplus_fast(acc + b2[tid]);
    }
    __syncthreads();
    if (tid == 0) {
        float acc = 0.f;
        for (int k = 0; k < 64; k++) acc += x2[k] * w3[k];
        out[b] = acc + b3[0];
    }
}

extern "C" void kernel_launch(void* const* d_in, const int* in_sizes, int n_in,
                              void* d_out, int out_size, void* d_ws, size_t ws_size,
                              hipStream_t stream) {
    const float* nf      = (const float*)d_in[0];
    const int*   ei      = (const int*)d_in[1];
    const float* ef      = (const float*)d_in[2];
    const int*   gi      = (const int*)d_in[3];
    const float* embed_w = (const float*)d_in[4];
    const float* embed_b = (const float*)d_in[5];
    const float* gate_w  = (const float*)d_in[6];
    const float* gate_b  = (const float*)d_in[7];
    const float* cand_w  = (const float*)d_in[8];
    const float* cand_b  = (const float*)d_in[9];
    const float* bn_g    = (const float*)d_in[10];
    const float* bn_b    = (const float*)d_in[11];
    const float* w1      = (const float*)d_in[12];
    const float* b1      = (const float*)d_in[13];
    const float* w2      = (const float*)d_in[14];
    const float* b2      = (const float*)d_in[15];
    const float* w3      = (const float*)d_in[16];
    const float* b3      = (const float*)d_in[17];
    float* out = (float*)d_out;

    const int NH = NN * HH;  // 6.4M
    char* p = (char*)d_ws;
    // --- zero-initialized block (single memset) ---
    int*       offs    = (int*)p;              p += (size_t)NN * 4;
    float*     agg     = (float*)p;            p += (size_t)(NN + 1) * HH * 4;  // +1 dummy row
    float*     stats   = (float*)p;            p += 3 * 128 * 4;
    float*     pool    = (float*)p;            p += (size_t)BB * HH * 4;
    float*     counts  = (float*)p;            p += (size_t)BB * 4;
    int*       sync    = (int*)p;              p += 8 * 4;   // [0..2]=bn, [3]=poolmlp, [4]=scan
    size_t zero_bytes = (size_t)(p - (char*)d_ws);
    // --- rest ---
    _Float16*  h16     = (_Float16*)p;         p += (size_t)(NN + 1) * HH * 2;  // +1 dummy row
    int*       ssorted = (int*)p;              p += (size_t)EPADTOT * 4;
    int2*      sdsorted= (int2*)p;             p += (size_t)EPADTOT * 8;
    _Float16*  ef16    = (_Float16*)p;         p += (size_t)EPADTOT * EFSTR * 2;
    int*       perm    = (int*)p;              p += (size_t)EE * 4;
    int*       rank    = (int*)p;              p += (size_t)EE * 4;
    _Float16*  wTall   = (_Float16*)p;         p += (size_t)3 * 128 * 160 * 2;
    int*       bsum    = (int*)p;              p += 512 * 4;

    const int* src = ei;
    const int* dst = ei + EE;

    hipMemsetAsync(d_ws, 0, zero_bytes, stream);

    // ---- fused prep: embed + hist/rank + weight prep + pad fill ----
    prep_kernel<<<PREP_TOT, 256, 0, stream>>>(
        nf, embed_w, embed_b, h16, src, offs, rank,
        gate_w, cand_w, wTall, ssorted, sdsorted, ef16);

    // ---- fused scan (block scan + last-block bsum scan) ----
    scan_kernel<<<NB1, 256, 0, stream>>>(offs, bsum, sync + 4);

    // ---- perm + gather (kept separate: cross-XCD plain-store visibility) ----
    perm_kernel<<<EE / 256, 256, 0, stream>>>(src, rank, offs, bsum, perm);
    gather_kernel<<<EE / 256, 256, 0, stream>>>(perm, src, dst, ef, ssorted, sdsorted, ef16);

    // ---- conv layers, fused BN ----
    for (int i = 0; i < N_CONV; i++) {
        edge_conv_mfma<<<NBLK, 128, 0, stream>>>(
            h16, ssorted, sdsorted, ef16,
            wTall + (size_t)i * 128 * 160,
            gate_b + i * HH, cand_b + i * HH, agg);
        bn_fused_kernel<<<SYNC_GRID, 256, 0, stream>>>(
            h16, agg, stats + i * 128, bn_g + i * HH, bn_b + i * HH,
            sync + i, 1.0f / (float)NN);
    }

    // ---- fused pool + MLP ----
    poolmlp_kernel<<<SYNC_GRID, 256, 0, stream>>>(
        h16, gi, pool, counts, sync + 3, w1, b1, w2, b2, w3, b3, out);
}

// Round 12
// 832.617 us; speedup vs baseline: 1.2162x; 1.2162x over previous
//
#include <hip/hip_runtime.h>
#include <hip/hip_bf16.h>

#define NN 100000
#define EE 1600000
#define BB 256
#define F_NODE 35
#define F_EDGE 10
#define HH 64
#define IN_DIM 138
#define N_CONV 3
#define EPSBN 1e-5f
#define NB1 ((NN + 255) / 256)  // 391 scan blocks

// conv tiling: 4000 blocks x 2 waves; block covers 400 edges (waves split cols).
// No padding: conv throughput is ~1.17ns/16-edge-unit regardless of grid shape
// (R8/R9/R10 normalization), so minimize total units.
#define NBLK 4000
#define NGROUPS 25
#define SUBLEN 100          // 4*NGROUPS
#define EPB 400             // 16*NGROUPS edges per block
#define EFSTR 12            // padded ef row in halves (24 B)

// fused hist+weightprep block ranges
#define HIST_BLKS (EE / 256)        // 6250
#define WPREP_BLKS 240              // 3*128*160/256

#define LOG2E 1.442695041f
#define LN2   0.6931471806f
// conv epilogue drops the *LN2 factor (BN scale-invariance); compensate in eps
#define EPSADJ (EPSBN / (LN2 * LN2))

typedef _Float16 half8 __attribute__((ext_vector_type(8)));
typedef float floatx4 __attribute__((ext_vector_type(4)));

__device__ __forceinline__ float softplus_fast(float x) {
    float t = __builtin_amdgcn_exp2f(fminf(LOG2E * x, 126.0f));
    return LN2 * __builtin_amdgcn_logf(1.0f + t);
}
// inputs pre-scaled: g2 = -log2e*g, c2 = log2e*c  ->  sigmoid(g)*log2(1+2^c2)
// NOTE: returns m_true/ln2 — uniform scale absorbed by BN (eps adjusted).
__device__ __forceinline__ float mpair_pre(float g2, float c2) {
    float tg = __builtin_amdgcn_exp2f(g2);
    float sig = __builtin_amdgcn_rcpf(1.0f + tg);
    float tc = __builtin_amdgcn_exp2f(fminf(c2, 126.0f));
    float l = __builtin_amdgcn_logf(1.0f + tc);
    return sig * l;
}

// ---------------- fused: hist+rank | weight-prep (disjoint block ranges) ----------------
__global__ __launch_bounds__(256)
void histw_kernel(const int* __restrict__ src, int* __restrict__ cnt,
                  int* __restrict__ rank,
                  const float* __restrict__ gw, const float* __restrict__ cw,
                  _Float16* __restrict__ wT) {
    int bid = blockIdx.x;
    int tid = threadIdx.x;
    if (bid < HIST_BLKS) {
        int e = bid * 256 + tid;
        rank[e] = atomicAdd(&cnt[src[e]], 1);
    } else {
        // weights -> f16 transposed [layer][n][k], pre-scaled by -/+log2e
        int idx = (bid - HIST_BLKS) * 256 + tid;
        int k = idx % 160;
        int n = (idx / 160) & 127;
        int layer = idx / (160 * 128);
        float v = 0.f;
        if (k < IN_DIM)
            v = (n < 64) ? (-LOG2E) * gw[layer * IN_DIM * HH + k * HH + n]
                         : ( LOG2E) * cw[layer * IN_DIM * HH + k * HH + (n - 64)];
        wT[idx] = (_Float16)v;
    }
}

__global__ __launch_bounds__(256)
void scan1_kernel(int* __restrict__ cnt, int* __restrict__ bsum, int n) {
    __shared__ int ls[256];
    int t = threadIdx.x;
    int i = blockIdx.x * 256 + t;
    int v = (i < n) ? cnt[i] : 0;
    ls[t] = v;
    __syncthreads();
#pragma unroll
    for (int off = 1; off < 256; off <<= 1) {
        int add = (t >= off) ? ls[t - off] : 0;
        __syncthreads();
        ls[t] += add;
        __syncthreads();
    }
    if (i < n) cnt[i] = ls[t] - v;
    if (t == 255) bsum[blockIdx.x] = ls[255];
}

__global__ __launch_bounds__(512)
void scan2_kernel(int* __restrict__ bsum, int nb) {
    __shared__ int ls[512];
    int t = threadIdx.x;
    int v = (t < nb) ? bsum[t] : 0;
    ls[t] = v;
    __syncthreads();
#pragma unroll
    for (int off = 1; off < 512; off <<= 1) {
        int add = (t >= off) ? ls[t - off] : 0;
        __syncthreads();
        ls[t] += add;
        __syncthreads();
    }
    if (t < nb) bsum[t] = ls[t] - v;
}

__global__ __launch_bounds__(256)
void perm_kernel(const int* __restrict__ src, const int* __restrict__ rank,
                 const int* __restrict__ offs, const int* __restrict__ bsum,
                 int* __restrict__ perm) {
    int e = blockIdx.x * 256 + threadIdx.x;
    int s = src[e];
    perm[offs[s] + bsum[s >> 8] + rank[e]] = e;
}

// coalesced-write gather: ssorted (epilogue int4), sd pairs (own-edge), ef16
__global__ __launch_bounds__(256)
void gather_kernel(const int* __restrict__ perm,
                   const int* __restrict__ src, const int* __restrict__ dst,
                   const float* __restrict__ ef,
                   int* __restrict__ ssorted, int2* __restrict__ sdsorted,
                   _Float16* __restrict__ ef16) {
    int pos = blockIdx.x * 256 + threadIdx.x;
    int e = perm[pos];
    int s = src[e], d = dst[e];
    ssorted[pos] = s;
    int2 sd; sd.x = s; sd.y = d;
    sdsorted[pos] = sd;
    const float2* efe = (const float2*)(ef + (size_t)e * F_EDGE);
    uint* op = (uint*)(ef16 + (size_t)pos * EFSTR);
#pragma unroll
    for (int i = 0; i < 5; i++) {
        float2 v = efe[i];
        _Float16 h0 = (_Float16)v.x;
        _Float16 h1 = (_Float16)v.y;
        op[i] = (uint)*(unsigned short*)&h0 | ((uint)*(unsigned short*)&h1 << 16);
    }
    op[5] = 0u;
}

// ---------------- embed (writes h16 only) ----------------
__global__ __launch_bounds__(256)
void embed_kernel(const float* __restrict__ nf, const float* __restrict__ w,
                  const float* __restrict__ bias, _Float16* __restrict__ h16, int n) {
    __shared__ float wl[F_NODE * HH];
    int tid = threadIdx.x;
    for (int i = tid; i < F_NODE * HH; i += 256) wl[i] = w[i];
    __syncthreads();
    int idx = blockIdx.x * 256 + tid;
    int node = idx >> 6, j = idx & 63;
    if (node >= n) return;
    float acc = bias[j];
    const float* row = nf + node * F_NODE;
#pragma unroll
    for (int k = 0; k < F_NODE; k++) acc += row[k] * wl[k * HH + j];
    h16[idx] = (_Float16)acc;
}

// ---------------- conv: R8 body (1-deep prefetch, barrier/LDS-free, col-split) ----------------
__device__ __forceinline__ void loadA(uint4* A,
                                      const _Float16* __restrict__ h16,
                                      const _Float16* __restrict__ ef16,
                                      int s, int d, int eg, int quad) {
    const uint4* hs = (const uint4*)(h16 + (size_t)s * HH);
    const uint4* hd = (const uint4*)(h16 + (size_t)d * HH);
    A[0] = hs[quad];
    A[1] = hs[quad + 4];
    A[2] = hd[quad];
    A[3] = hd[quad + 4];
    uint4 z; z.x = z.y = z.z = z.w = 0u;
    A[4] = z;
    const _Float16* p = ef16 + (size_t)eg * EFSTR;
    if (quad == 0) {
        uint2 a = *(const uint2*)p;
        uint2 b = *(const uint2*)(p + 4);
        A[4].x = a.x; A[4].y = a.y; A[4].z = b.x; A[4].w = b.y;
    } else if (quad == 1) {
        uint2 a = *(const uint2*)(p + 8);
        A[4].x = a.x; A[4].y = a.y;
    }
}

__global__ __launch_bounds__(128, 3)
void edge_conv_mfma(const _Float16* __restrict__ h16,
                    const int* __restrict__ ssorted,
                    const int2* __restrict__ sdsorted,
                    const _Float16* __restrict__ ef16,
                    const _Float16* __restrict__ wT,
                    const float* __restrict__ gb, const float* __restrict__ cb,
                    float* __restrict__ agg) {
    int lane = threadIdx.x & 63;
    int w = threadIdx.x >> 6;          // wave 0/1: col-split
    int quad = lane >> 4, n15 = lane & 15;
    int blockE = blockIdx.x * EPB;
    int base = blockE + ((n15 >> 2) * SUBLEN) + (n15 & 3);
    int ebase_epi = blockE + quad * SUBLEN;   // + g*4 + r : this lane's C rows

    int tg = 2 * w;
    half8 B[4][5];
#pragma unroll
    for (int j = 0; j < 2; j++) {
        const _Float16* wrg = wT + ((tg + j) * 16 + n15) * 160 + quad * 8;
        const _Float16* wrc = wT + ((4 + tg + j) * 16 + n15) * 160 + quad * 8;
#pragma unroll
        for (int ks = 0; ks < 5; ks++) {
            B[j][ks]     = *(const half8*)(wrg + ks * 32);
            B[2 + j][ks] = *(const half8*)(wrc + ks * 32);
        }
    }
    float gb0 = -LOG2E * gb[tg * 16 + n15], gb1 = -LOG2E * gb[(tg + 1) * 16 + n15];
    float cb0 =  LOG2E * cb[tg * 16 + n15], cb1 =  LOG2E * cb[(tg + 1) * 16 + n15];
    int colbase = tg * 16 + n15;

    int sprev = -1;
    float am0 = 0.f, am1 = 0.f;

    uint4 A[5];
    {
        int2 sd0 = sdsorted[base];
        loadA(A, h16, ef16, sd0.x, sd0.y, base, quad);
    }
    int2 sdn = sdsorted[base + 4];

    for (int g = 0; g < NGROUPS; g++) {
        int4 ss = *(const int4*)&ssorted[ebase_epi + g * 4];

        floatx4 acc[4];
        acc[0] = (floatx4){gb0, gb0, gb0, gb0};
        acc[1] = (floatx4){gb1, gb1, gb1, gb1};
        acc[2] = (floatx4){cb0, cb0, cb0, cb0};
        acc[3] = (floatx4){cb1, cb1, cb1, cb1};

#pragma unroll
        for (int ks = 0; ks < 5; ks++) {
            half8 a = __builtin_bit_cast(half8, A[ks]);
#pragma unroll
            for (int t = 0; t < 4; t++)
                acc[t] = __builtin_amdgcn_mfma_f32_16x16x32_f16(a, B[t][ks], acc[t], 0, 0, 0);
        }

        int gl = (g + 1 < NGROUPS) ? g + 1 : NGROUPS - 1;
        loadA(A, h16, ef16, sdn.x, sdn.y, base + gl * 4, quad);
        int gp = (g + 2 < NGROUPS) ? g + 2 : NGROUPS - 1;
        sdn = sdsorted[base + gp * 4];

        float mm0[4], mm1[4];
#pragma unroll
        for (int r = 0; r < 4; r++) {
            mm0[r] = mpair_pre(acc[0][r], acc[2][r]);
            mm1[r] = mpair_pre(acc[1][r], acc[3][r]);
        }
        int srr[4] = {ss.x, ss.y, ss.z, ss.w};
#pragma unroll
        for (int r = 0; r < 4; r++) {
            int sr = srr[r];
            if (sr != sprev) {
                if (sprev >= 0) {
                    float* p = agg + (size_t)sprev * HH + colbase;
                    atomicAdd(p, am0);
                    atomicAdd(p + 16, am1);
                }
                sprev = sr;
                am0 = am1 = 0.f;
            }
            am0 += mm0[r];   // scaled by 1/ln2; BN eps-adjusted
            am1 += mm1[r];
        }
    }
    if (sprev >= 0) {
        float* p = agg + (size_t)sprev * HH + colbase;
        atomicAdd(p, am0);
        atomicAdd(p + 16, am1);
    }
}

// ---------------- BN ----------------
__global__ __launch_bounds__(256)
void bn_stats_kernel(const float* __restrict__ agg, float* __restrict__ stats, int total) {
    __shared__ float ls[256], lss[256];
    int tid = threadIdx.x;
    float s = 0.f, ss = 0.f;
    for (int idx = blockIdx.x * 256 + tid; idx < total; idx += gridDim.x * 256) {
        float v = agg[idx];
        s += v;
        ss += v * v;
    }
    ls[tid] = s;
    lss[tid] = ss;
    __syncthreads();
    if (tid < 64) {
        s = ls[tid] + ls[tid + 64] + ls[tid + 128] + ls[tid + 192];
        ss = lss[tid] + lss[tid + 64] + lss[tid + 128] + lss[tid + 192];
        atomicAdd(&stats[tid], s);
        atomicAdd(&stats[64 + tid], ss);
    }
}

// h16 = softplus(h16 + BN(agg)); zeroes agg for next layer.
// agg is scaled by 1/ln2 -> use eps/ln2^2 for exact equivalence.
__global__ __launch_bounds__(256)
void bn_update_kernel(_Float16* __restrict__ h16,
                      float* __restrict__ agg,
                      const float* __restrict__ stats,
                      const float* __restrict__ g, const float* __restrict__ b,
                      int total, float invN) {
    int idx = blockIdx.x * 256 + threadIdx.x;
    if (idx >= total) return;
    int j = idx & 63;
    float mu = stats[j] * invN;
    float var = stats[64 + j] * invN - mu * mu;
    var = fmaxf(var, 0.0f);
    float scale = g[j] * rsqrtf(var + EPSADJ);
    float a = agg[idx];
    agg[idx] = 0.f;
    float v = (float)h16[idx] + (a - mu) * scale + b[j];
    h16[idx] = (_Float16)softplus_fast(v);
}

// ---------------- pool (reads h16) ----------------
__global__ __launch_bounds__(256)
void pool_kernel(const _Float16* __restrict__ h16, const int* __restrict__ gi,
                 float* __restrict__ pool, float* __restrict__ counts, int n) {
    int tid = threadIdx.x;
    int grp = tid >> 6;
    int j = tid & 63;
    int n0 = blockIdx.x * 64 + grp * 16;
    if (n0 >= n) return;
    int nend = n0 + 16; if (nend > n) nend = n;
    int gprev = gi[n0];
    float a = 0.f;
    int cnt = 0;
    for (int nn = n0; nn < nend; nn++) {
        int gg = gi[nn];
        if (gg != gprev) {
            atomicAdd(&pool[gprev * 64 + j], a);
            if (j == 0) atomicAdd(&counts[gprev], (float)cnt);
            a = 0.f; cnt = 0; gprev = gg;
        }
        a += (float)h16[(size_t)nn * 64 + j];
        cnt++;
    }
    atomicAdd(&pool[gprev * 64 + j], a);
    if (j == 0) atomicAdd(&counts[gprev], (float)cnt);
}

__global__ __launch_bounds__(128)
void mlp_kernel(const float* __restrict__ pool, const float* __restrict__ counts,
                const float* __restrict__ w1, const float* __restrict__ b1,
                const float* __restrict__ w2, const float* __restrict__ b2,
                const float* __restrict__ w3, const float* __restrict__ b3,
                float* __restrict__ out) {
    __shared__ float x0[64], x1[128], x2[64];
    int b = blockIdx.x, t = threadIdx.x;
    if (t < 64) {
        float c = counts[b];
        c = c < 1.f ? 1.f : c;
        x0[t] = pool[b * 64 + t] / c;
    }
    __syncthreads();
    {
        float acc = 0.f;
#pragma unroll
        for (int k = 0; k < 64; k++) acc += x0[k] * w1[k * 128 + t];
        x1[t] = softplus_fast(acc + b1[t]);
    }
    __syncthreads();
    if (t < 64) {
        float acc = 0.f;
#pragma unroll
        for (int k = 0; k < 128; k++) acc += x1[k] * w2[k * 64 + t];
        x2[t] = softplus_fast(acc + b2[t]);
    }
    __syncthreads();
    if (t == 0) {
        float acc = 0.f;
        for (int k = 0; k < 64; k++) acc += x2[k] * w3[k];
        out[b] = acc + b3[0];
    }
}

extern "C" void kernel_launch(void* const* d_in, const int* in_sizes, int n_in,
                              void* d_out, int out_size, void* d_ws, size_t ws_size,
                              hipStream_t stream) {
    const float* nf      = (const float*)d_in[0];
    const int*   ei      = (const int*)d_in[1];
    const float* ef      = (const float*)d_in[2];
    const int*   gi      = (const int*)d_in[3];
    const float* embed_w = (const float*)d_in[4];
    const float* embed_b = (const float*)d_in[5];
    const float* gate_w  = (const float*)d_in[6];
    const float* gate_b  = (const float*)d_in[7];
    const float* cand_w  = (const float*)d_in[8];
    const float* cand_b  = (const float*)d_in[9];
    const float* bn_g    = (const float*)d_in[10];
    const float* bn_b    = (const float*)d_in[11];
    const float* w1      = (const float*)d_in[12];
    const float* b1      = (const float*)d_in[13];
    const float* w2      = (const float*)d_in[14];
    const float* b2      = (const float*)d_in[15];
    const float* w3      = (const float*)d_in[16];
    const float* b3      = (const float*)d_in[17];
    float* out = (float*)d_out;

    const int NH = NN * HH;  // 6.4M
    char* p = (char*)d_ws;
    // --- zero-initialized block (single memset) ---
    int*       offs    = (int*)p;              p += (size_t)NN * 4;
    float*     agg     = (float*)p;            p += (size_t)NH * 4;
    float*     stats   = (float*)p;            p += 3 * 128 * 4;
    float*     pool    = (float*)p;            p += (size_t)BB * HH * 4;
    float*     counts  = (float*)p;            p += (size_t)BB * 4;
    size_t zero_bytes = (size_t)(p - (char*)d_ws);
    // --- rest ---
    _Float16*  h16     = (_Float16*)p;         p += (size_t)NH * 2;
    int*       ssorted = (int*)p;              p += (size_t)EE * 4;
    int2*      sdsorted= (int2*)p;             p += (size_t)EE * 8;
    _Float16*  ef16    = (_Float16*)p;         p += (size_t)EE * EFSTR * 2;
    int*       perm    = (int*)p;              p += (size_t)EE * 4;
    int*       rank    = (int*)p;              p += (size_t)EE * 4;
    _Float16*  wTall   = (_Float16*)p;         p += (size_t)3 * 128 * 160 * 2;
    int*       bsum    = (int*)p;              p += 512 * 4;

    const int* src = ei;
    const int* dst = ei + EE;

    hipMemsetAsync(d_ws, 0, zero_bytes, stream);

    // ---- sort edges by src + weight prep (hist and wprep fused, disjoint ranges) ----
    histw_kernel<<<HIST_BLKS + WPREP_BLKS, 256, 0, stream>>>(
        src, offs, rank, gate_w, cand_w, wTall);
    scan1_kernel<<<NB1, 256, 0, stream>>>(offs, bsum, NN);
    scan2_kernel<<<1, 512, 0, stream>>>(bsum, NB1);
    perm_kernel<<<EE / 256, 256, 0, stream>>>(src, rank, offs, bsum, perm);
    gather_kernel<<<EE / 256, 256, 0, stream>>>(perm, src, dst, ef, ssorted, sdsorted, ef16);

    // ---- embed ----
    embed_kernel<<<NH / 256, 256, 0, stream>>>(nf, embed_w, embed_b, h16, NN);

    // ---- conv layers ----
    for (int i = 0; i < N_CONV; i++) {
        edge_conv_mfma<<<NBLK, 128, 0, stream>>>(
            h16, ssorted, sdsorted, ef16,
            wTall + (size_t)i * 128 * 160,
            gate_b + i * HH, cand_b + i * HH, agg);
        bn_stats_kernel<<<512, 256, 0, stream>>>(agg, stats + i * 128, NH);
        bn_update_kernel<<<NH / 256, 256, 0, stream>>>(
            h16, agg, stats + i * 128, bn_g + i * HH, bn_b + i * HH, NH, 1.0f / (float)NN);
    }

    // ---- pool + MLP ----
    pool_kernel<<<(NN + 63) / 64, 256, 0, stream>>>(h16, gi, pool, counts, NN);
    mlp_kernel<<<BB, 128, 0, stream>>>(pool, counts, w1, b1, w2, b2, w3, b3, out);
}